// Round 2
// baseline (336.685 us; speedup 1.0000x reference)
//
#include <hip/hip_runtime.h>

#define NN 50000
#define EE 800000
#define FF 256     // IN_F == ATT_D
#define HH 8
#define DK 32

typedef short bf16x8 __attribute__((ext_vector_type(8)));
typedef float f32x4  __attribute__((ext_vector_type(4)));

__device__ __forceinline__ float b2f(short s) {
    return __uint_as_float(((unsigned)(unsigned short)s) << 16);
}
__device__ __forceinline__ short f2b(float f) {          // RNE
    unsigned u = __float_as_uint(f);
    return (short)((u + 0x7fff + ((u >> 16) & 1)) >> 16);
}

// global -> LDS direct copy, 16 B per lane. LDS dest is wave-uniform base;
// HW adds lane*16. Global src is per-lane.
__device__ __forceinline__ void gld16(void* lds, const void* g) {
    __builtin_amdgcn_global_load_lds(
        (const __attribute__((address_space(1))) unsigned int*)g,
        (__attribute__((address_space(3))) unsigned int*)lds,
        16, 0, 0);
}

// ---------------------------------------------------------------------------
// One-launch sniffer: blocks 0..7 test float arrays (fp32 vs bf16), block 8
// tests edge width (int64 vs int32). fp32 read as shorts: even shorts are
// mantissa low-halves -> ~25% have exponent field >= 0xC0; bf16 data never.
// int64 node ids < 50000 -> high words all zero.
// ---------------------------------------------------------------------------
__global__ __launch_bounds__(256) void sniff_all(
    const void* x, const void* ew, const void* wq, const void* bq,
    const void* wk, const void* bk, const void* wv, const void* bv,
    const void* edge, int* __restrict__ flags)
{
    __shared__ int tot;
    if (threadIdx.x == 0) tot = 0;
    __syncthreads();
    int b = blockIdx.x;
    if (b < 8) {
        const void* ptrs[8] = {x, ew, wq, bq, wk, bk, wv, bv};
        const int   ns[8]   = {NN * FF, EE, FF * FF, FF, FF * FF, FF, FF * FF, FF};
        const unsigned short* p = (const unsigned short*)ptrs[b];
        int half = ns[b] >> 1;
        int S = half < 4096 ? half : 4096;
        int cnt = 0;
        for (int i = threadIdx.x; i < S; i += 256) {
            unsigned v = p[2 * i];
            cnt += (((v >> 7) & 0xFF) >= 0xC0) ? 1 : 0;
        }
        atomicAdd(&tot, cnt);
        __syncthreads();
        if (threadIdx.x == 0) flags[b] = (tot * 32 > S) ? 1 : 0;   // 1 = fp32
    } else {
        const unsigned* e32 = (const unsigned*)edge;
        int cnt = 0;
        for (int i = threadIdx.x; i < 4096; i += 256)
            cnt += (e32[2 * i + 1] != 0u) ? 1 : 0;
        atomicAdd(&tot, cnt);
        __syncthreads();
        if (threadIdx.x == 0) flags[8] = (tot < 100) ? 1 : 0;      // 1 = int64
    }
}

// ---------------------------------------------------------------------------
// Pre-convert Wq/Wk/Wv -> bf16 in a K-step-slab-major, swizzled-chunk layout
// that qkv_gemm stages verbatim into LDS with global_load_lds:
//   wb[mat] = 8 slabs (one per K-step s, 16 KB each). Within a slab, the
//   16 B chunk holding W[row][s*32 + quad*8 .. +8] lives at chunk index
//   p = row*4 + (quad ^ ((row>>1)&3)).  The XOR spreads the 16 fragment
//   lanes (stride-64B rows) across all 8 LDS chunk-slots -> conflict-free
//   ds_read_b128 under either LDS phasing model.  Biases -> f32.
// ---------------------------------------------------------------------------
__global__ __launch_bounds__(256) void convert_wb(
    const void* wq, const void* wk, const void* wv,
    const void* bq, const void* bk, const void* bv,
    short* __restrict__ wb, float* __restrict__ bb,
    const int* __restrict__ flags)
{
    int b = blockIdx.x;
    if (b < 96) {
        int mat = b >> 5;
        const void* src = mat == 0 ? wq : mat == 1 ? wk : wv;
        int isf = flags[2 + mat * 2];
        int base = (b & 31) * 2048 + threadIdx.x * 8;   // linear src offset (shorts)
        bf16x8 v;
        if (isf) {
            const f32x4* pp = (const f32x4*)((const float*)src + base);
            f32x4 a = pp[0], c = pp[1];
            #pragma unroll
            for (int j = 0; j < 4; ++j) { v[j] = f2b(a[j]); v[4 + j] = f2b(c[j]); }
        } else {
            v = *(const bf16x8*)((const short*)src + base);
        }
        int row = base >> 8, k = base & 255;            // W is [256 out][256 k]
        int s = k >> 5, quad = (k >> 3) & 3;
        int pc = (row << 2) + (quad ^ ((row >> 1) & 3));
        *(bf16x8*)(wb + mat * (FF * FF) + s * 8192 + pc * 8) = v;
    } else {
        #pragma unroll
        for (int mat = 0; mat < 3; ++mat) {
            const void* src = mat == 0 ? bq : mat == 1 ? bk : bv;
            int isf = flags[3 + mat * 2];
            int i = threadIdx.x;
            bb[mat * FF + i] = isf ? ((const float*)src)[i]
                                   : b2f(((const short*)src)[i]);
        }
    }
}

// ---------------------------------------------------------------------------
// Projection GEMM, mat-fused: block = 64 rows, 4 waves of 16 rows x 256 cols.
// x fragments for ALL 8 K-steps preloaded into registers ONCE (afrag[8],
// 32 VGPRs, bit-identical values) -> x leaves HBM exactly once per block
// regardless of how many matrices [mlo,mhi] the block computes.  Per mat:
// 8-step K-loop, double-buffered 16 KB W slabs staged via global_load_lds,
// ds_read_b128 fragments + 16 MFMA per step, one __syncthreads per step.
// LDS = 32 KB; epilogue reuses it (8 KB wave-private) for coalesced stores.
// ---------------------------------------------------------------------------
__global__ __launch_bounds__(256) void qkv_gemm(
    const void* __restrict__ x, const short* __restrict__ wb,
    const float* __restrict__ bb, short* __restrict__ qo,
    short* __restrict__ ko, float* __restrict__ vo,
    const int* __restrict__ flags, int mlo, int mhi)
{
    __shared__ __align__(16) short wlds[2][8192];       // 2 x 16 KB W slabs
    const int isf32x = flags[0];
    const int tid = threadIdx.x, wave = tid >> 6, lane = tid & 63;
    const int l16 = lane & 15, quad = lane >> 4;
    const int rows0 = blockIdx.x * 64 + wave * 16;
    const int rowa = rows0 + l16;
    const int rowc = rowa < NN ? rowa : NN - 1;
    const int koff = quad * 8;
    const size_t xrow = (size_t)rowc * FF;

    // per-lane ds_read offset within a slab (shorts); +c*512 per fragment
    const int rdo = l16 * 32 + ((quad ^ ((l16 >> 1) & 3)) << 3);

    // ---- preload x fragments for all 8 K-steps (read x once per block) ----
    bf16x8 afrag[8];
    if (isf32x) {
        f32x4 t0[8], t1[8];
        #pragma unroll
        for (int s = 0; s < 8; ++s) {
            const f32x4* p = (const f32x4*)((const float*)x + xrow + s * 32 + koff);
            t0[s] = p[0]; t1[s] = p[1];
        }
        #pragma unroll
        for (int s = 0; s < 8; ++s)
            #pragma unroll
            for (int j = 0; j < 4; ++j) {
                afrag[s][j]     = f2b(t0[s][j]);
                afrag[s][4 + j] = f2b(t1[s][j]);
            }
    } else {
        #pragma unroll
        for (int s = 0; s < 8; ++s)
            afrag[s] = *(const bf16x8*)((const short*)x + xrow + s * 32 + koff);
    }

    // stage slab s of W into buffer buf: 1024 chunks of 16 B, 4/thread;
    // wave-uniform LDS base = chunk (i*256 + wave*64), lane adds +lane.
    #define STAGE(buf, W_, s) do {                                              \
        const short* gs_ = (W_) + (s) * 8192;                                   \
        _Pragma("unroll")                                                       \
        for (int i_ = 0; i_ < 4; ++i_)                                          \
            gld16(&wlds[buf][(i_ * 256 + (tid & ~63)) * 8],                     \
                  gs_ + (size_t)(i_ * 256 + tid) * 8);                          \
    } while (0)

    for (int mat = mlo; mat <= mhi; ++mat) {
        const short* W = wb + mat * (FF * FF);          // slab-major
        if (mat != mlo) __syncthreads();                // prev epilogue LDS reads done
        STAGE(0, W, 0);
        __syncthreads();                                // slab 0 resident

        f32x4 acc[16] = {};
        #pragma unroll
        for (int s = 0; s < 8; ++s) {
            const int cur = s & 1;
            if (s < 7) STAGE(cur ^ 1, W, s + 1);
            const short* ws0 = &wlds[cur][rdo];
            #pragma unroll
            for (int c = 0; c < 16; ++c) {
                bf16x8 bf = *(const bf16x8*)(ws0 + c * 512);
                acc[c] = __builtin_amdgcn_mfma_f32_16x16x32_bf16(afrag[s], bf, acc[c], 0, 0, 0);
            }
            __syncthreads();   // all waves done with cur; next slab drained
        }

        // ---- epilogue: reuse wlds; 8 KB wave-private slice ----
        // C/D layout: col = c*16 + (lane&15), row = quad*4 + reg  [m89-verified]
        const float* bias = bb + mat * FF;
        short* slice = (short*)wlds + wave * 4096;      // 8 KB per wave

        if (mat == 2) {
            // V: fp32, permuted cols pc = (col&31)*8 + col>>5.  Two rounds
            // split by c&1 -> contiguous 512 B per row per round.
            float* lsf = (float*)slice;                 // 16 rows x 128 floats
            #pragma unroll
            for (int h = 0; h < 2; ++h) {
                #pragma unroll
                for (int ci = 0; ci < 8; ++ci) {
                    int c = ci * 2 + h;                 // c & 1 == h
                    int col = c * 16 + l16;
                    float bv = bias[col];
                    int pcl = l16 * 8 + ci;             // pc - h*128, in [0,128)
                    #pragma unroll
                    for (int rr = 0; rr < 4; ++rr)
                        lsf[(quad * 4 + rr) * 128 + pcl] = acc[c][rr] + bv;
                }
                #pragma unroll
                for (int it = 0; it < 8; ++it) {        // 512 chunks of 16 B
                    int idx = it * 64 + lane;
                    int r = idx >> 5, cc = idx & 31;
                    int row = rows0 + r;
                    if (row < NN)
                        *(f32x4*)(vo + (size_t)row * FF + h * 128 + cc * 4) =
                            ((const f32x4*)lsf)[idx];
                }
            }
        } else {
            // Q/K: bf16, 16 rows x 256 shorts = 8 KB exact.
            #pragma unroll
            for (int c = 0; c < 16; ++c) {
                int col = c * 16 + l16;
                float bv = bias[col];
                #pragma unroll
                for (int rr = 0; rr < 4; ++rr)
                    slice[(quad * 4 + rr) * 256 + col] = f2b(acc[c][rr] + bv);
            }
            short* out = (mat == 0) ? qo : ko;
            #pragma unroll
            for (int it = 0; it < 8; ++it) {            // 512 chunks of 16 B
                int idx = it * 64 + lane;
                int r = idx >> 5, cc = idx & 31;
                int row = rows0 + r;
                if (row < NN)
                    *(bf16x8*)(out + (size_t)row * FF + cc * 8) =
                        *(const bf16x8*)(slice + r * 256 + cc * 8);
            }
        }
    }
    #undef STAGE
}

// ---------------------------------------------------------------------------
// Edge phase. Pass A: exp -> (optional ws stage) + atomicAdd into sums.
// rsum: sums -> 1/(sums+eps) in place. Pass B: att = exp * rsum (exp from
// ws if staged, else recomputed bit-identically). Segment-max skipped:
// logits ~ N(0,~0.1), overflow-free.
// ---------------------------------------------------------------------------
__device__ __forceinline__ float edge_exp_f(
    const int* __restrict__ edge, const void* __restrict__ ew,
    const short* __restrict__ q, const short* __restrict__ k,
    int t, int isf32, int is64, int* s_out)
{
    int e = t >> 3, h = t & 7;
    int s = is64 ? edge[2 * (size_t)e] : edge[e];
    int d = is64 ? edge[2 * ((size_t)EE + e)] : edge[EE + e];
    *s_out = s;
    const short* qp = q + (size_t)s * FF + h * DK;
    const short* kp = k + (size_t)d * FF + h * DK;
    float dot = 0.f;
    #pragma unroll
    for (int i = 0; i < 4; ++i) {
        bf16x8 qa = *(const bf16x8*)(qp + i * 8);
        bf16x8 ka = *(const bf16x8*)(kp + i * 8);
        #pragma unroll
        for (int j = 0; j < 8; ++j) dot += b2f(qa[j]) * b2f(ka[j]);
    }
    float w = isf32 ? ((const float*)ew)[e] : b2f(((const short*)ew)[e]);
    return __expf(dot * 0.17677669529663687f * w);   // 1/sqrt(32)
}

__global__ __launch_bounds__(256) void edge_pass_a(
    const int* __restrict__ edge, const void* __restrict__ ew,
    const short* __restrict__ q, const short* __restrict__ k,
    float* __restrict__ sums, float* __restrict__ expbuf,
    const int* __restrict__ flags, int use_exp)
{
    int t = blockIdx.x * 256 + threadIdx.x;   // t < E*H exactly
    int s;
    float exv = edge_exp_f(edge, ew, q, k, t, flags[1], flags[8], &s);
    if (use_exp) expbuf[t] = exv;
    atomicAdd(&sums[s * HH + (threadIdx.x & 7)], exv);
}

__global__ __launch_bounds__(256) void rsum_inv(float* __restrict__ sums)
{
    int i = blockIdx.x * 256 + threadIdx.x;
    if (i < NN * HH) sums[i] = 1.0f / (sums[i] + 1e-16f);
}

__global__ __launch_bounds__(256) void edge_pass_b(
    const int* __restrict__ edge, const void* __restrict__ ew,
    const short* __restrict__ q, const short* __restrict__ k,
    const float* __restrict__ sums, const float* __restrict__ expbuf,
    float* __restrict__ att, const int* __restrict__ flags, int use_exp)
{
    int t = blockIdx.x * 256 + threadIdx.x;
    float exv; int s;
    if (use_exp) {
        int e = t >> 3;
        s = flags[8] ? edge[2 * (size_t)e] : edge[e];
        exv = expbuf[t];
    } else {
        exv = edge_exp_f(edge, ew, q, k, t, flags[1], flags[8], &s);
    }
    att[t] = exv * sums[s * HH + (t & 7)];
}

extern "C" void kernel_launch(void* const* d_in, const int* in_sizes, int n_in,
                              void* d_out, int out_size, void* d_ws, size_t ws_size,
                              hipStream_t stream) {
    const void* x    = d_in[0];
    const int*  edge = (const int*)d_in[1];
    const void* ew   = d_in[2];
    const void* Wq   = d_in[3];
    const void* bq   = d_in[4];
    const void* Wk   = d_in[5];
    const void* bk   = d_in[6];
    const void* Wv   = d_in[7];
    const void* bv   = d_in[8];

    float* att_out = (float*)d_out;                 // fp32 [E,H]
    float* v_out   = att_out + (size_t)EE * HH;     // fp32 [N,DK,H]

    // ws: flags(256B) | sums N*H f32 | q_ bf16 | wb bf16 x3 | bb f32 x3 |
    //     expb f32 [E,H]? | k_ bf16?
    char*  ws    = (char*)d_ws;
    int*   flags = (int*)ws;
    float* sums  = (float*)(ws + 256);
    const size_t SUMS_B = (size_t)NN * HH * 4;      // 1.6 MB
    const size_t Q_B    = (size_t)NN * FF * 2;      // 25.6 MB
    const size_t EXP_B  = (size_t)EE * HH * 4;      // 25.6 MB
    short* q_  = (short*)(ws + 256 + SUMS_B);
    short* wb  = (short*)(ws + 256 + SUMS_B + Q_B);
    float* bb  = (float*)(ws + 256 + SUMS_B + Q_B + 3 * FF * FF * 2);
    float* expb = (float*)(ws + 256 + SUMS_B + Q_B + 3 * FF * FF * 2 + 3 * FF * 4);
    const size_t BASE_B = 256 + SUMS_B + Q_B + 3 * FF * FF * 2 + 3 * FF * 4;
    const int use_exp = (ws_size >= BASE_B + EXP_B) ? 1 : 0;
    const int fused   = (ws_size >= BASE_B + EXP_B + Q_B) ? 1 : 0;

    sniff_all<<<9, 256, 0, stream>>>(x, ew, Wq, bq, Wk, bk, Wv, bv, edge, flags);
    convert_wb<<<97, 256, 0, stream>>>(Wq, Wk, Wv, bq, bk, bv, wb, bb, flags);
    hipMemsetAsync(sums, 0, SUMS_B, stream);

    const int nEH = EE * HH;                        // 6.4M, % 256 == 0
    dim3 g((NN + 63) / 64);

    if (fused) {
        // k_ lives in ws -> single QKV GEMM dispatch, x read once.
        short* k_ = (short*)(ws + BASE_B + EXP_B);
        qkv_gemm<<<g, 256, 0, stream>>>(x, wb, bb, q_, k_, v_out, flags, 0, 2);
        edge_pass_a<<<nEH / 256, 256, 0, stream>>>(edge, ew, q_, k_, sums, expb, flags, 1);
        rsum_inv<<<(NN * HH + 255) / 256, 256, 0, stream>>>(sums);
        edge_pass_b<<<nEH / 256, 256, 0, stream>>>(edge, ew, q_, k_, sums, expb, att_out, flags, 1);
    } else {
        // K staged bf16 inside the fp32 v-output region; V GEMM runs last.
        short* k_ = (short*)v_out;
        qkv_gemm<<<g, 256, 0, stream>>>(x, wb, bb, q_, k_, nullptr, flags, 0, 1);
        edge_pass_a<<<nEH / 256, 256, 0, stream>>>(edge, ew, q_, k_, sums, expb, flags, use_exp);
        rsum_inv<<<(NN * HH + 255) / 256, 256, 0, stream>>>(sums);
        edge_pass_b<<<nEH / 256, 256, 0, stream>>>(edge, ew, q_, k_, sums, expb, att_out, flags, use_exp);
        qkv_gemm<<<g, 256, 0, stream>>>(x, wb, bb, nullptr, nullptr, v_out, flags, 2, 2);
    }
}

// Round 3
// 304.216 us; speedup vs baseline: 1.1067x; 1.1067x over previous
//
#include <hip/hip_runtime.h>

#define NN 50000
#define EE 800000
#define FF 256     // IN_F == ATT_D
#define HH 8
#define DK 32

typedef short bf16x8 __attribute__((ext_vector_type(8)));
typedef float f32x4  __attribute__((ext_vector_type(4)));

__device__ __forceinline__ float b2f(short s) {
    return __uint_as_float(((unsigned)(unsigned short)s) << 16);
}
__device__ __forceinline__ short f2b(float f) {          // RNE
    unsigned u = __float_as_uint(f);
    return (short)((u + 0x7fff + ((u >> 16) & 1)) >> 16);
}

// global -> LDS direct copy, 16 B per lane. LDS dest is wave-uniform base;
// HW adds lane*16. Global src is per-lane.
__device__ __forceinline__ void gld16(void* lds, const void* g) {
    __builtin_amdgcn_global_load_lds(
        (const __attribute__((address_space(1))) unsigned int*)g,
        (__attribute__((address_space(3))) unsigned int*)lds,
        16, 0, 0);
}

// m204 bijective XCD swizzle: physical bid (round-robin across 8 XCDs) ->
// logical work id such that each XCD owns a CONTIGUOUS logical chunk.
__device__ __forceinline__ int xcd_swz(int bid, int nwg) {
    int q = nwg >> 3, r = nwg & 7, x = bid & 7, i = bid >> 3;
    int base = x < r ? x * (q + 1) : r * (q + 1) + (x - r) * q;
    return base + i;
}

// ---------------------------------------------------------------------------
// One-launch sniffer: blocks 0..7 test float arrays (fp32 vs bf16), block 8
// tests edge width (int64 vs int32). fp32 read as shorts: even shorts are
// mantissa low-halves -> ~25% have exponent field >= 0xC0; bf16 data never.
// int64 node ids < 50000 -> high words all zero.
// ---------------------------------------------------------------------------
__global__ __launch_bounds__(256) void sniff_all(
    const void* x, const void* ew, const void* wq, const void* bq,
    const void* wk, const void* bk, const void* wv, const void* bv,
    const void* edge, int* __restrict__ flags)
{
    __shared__ int tot;
    if (threadIdx.x == 0) tot = 0;
    __syncthreads();
    int b = blockIdx.x;
    if (b < 8) {
        const void* ptrs[8] = {x, ew, wq, bq, wk, bk, wv, bv};
        const int   ns[8]   = {NN * FF, EE, FF * FF, FF, FF * FF, FF, FF * FF, FF};
        const unsigned short* p = (const unsigned short*)ptrs[b];
        int half = ns[b] >> 1;
        int S = half < 4096 ? half : 4096;
        int cnt = 0;
        for (int i = threadIdx.x; i < S; i += 256) {
            unsigned v = p[2 * i];
            cnt += (((v >> 7) & 0xFF) >= 0xC0) ? 1 : 0;
        }
        atomicAdd(&tot, cnt);
        __syncthreads();
        if (threadIdx.x == 0) flags[b] = (tot * 32 > S) ? 1 : 0;   // 1 = fp32
    } else {
        const unsigned* e32 = (const unsigned*)edge;
        int cnt = 0;
        for (int i = threadIdx.x; i < 4096; i += 256)
            cnt += (e32[2 * i + 1] != 0u) ? 1 : 0;
        atomicAdd(&tot, cnt);
        __syncthreads();
        if (threadIdx.x == 0) flags[8] = (tot < 100) ? 1 : 0;      // 1 = int64
    }
}

// ---------------------------------------------------------------------------
// Pre-convert Wq/Wk/Wv -> bf16 in a K-step-slab-major, swizzled-chunk layout
// that qkv_gemm stages verbatim into LDS with global_load_lds:
//   wb[mat] = 8 slabs (one per K-step s, 16 KB each). Within a slab, the
//   16 B chunk holding W[row][s*32 + quad*8 .. +8] lives at chunk index
//   p = row*4 + (quad ^ ((row>>1)&3)).  The XOR spreads the 16 fragment
//   lanes (stride-64B rows) across all 8 LDS chunk-slots -> conflict-free
//   ds_read_b128 under either LDS phasing model.  Biases -> f32.
// ---------------------------------------------------------------------------
__global__ __launch_bounds__(256) void convert_wb(
    const void* wq, const void* wk, const void* wv,
    const void* bq, const void* bk, const void* bv,
    short* __restrict__ wb, float* __restrict__ bb,
    const int* __restrict__ flags)
{
    int b = blockIdx.x;
    if (b < 96) {
        int mat = b >> 5;
        const void* src = mat == 0 ? wq : mat == 1 ? wk : wv;
        int isf = flags[2 + mat * 2];
        int base = (b & 31) * 2048 + threadIdx.x * 8;   // linear src offset (shorts)
        bf16x8 v;
        if (isf) {
            const f32x4* pp = (const f32x4*)((const float*)src + base);
            f32x4 a = pp[0], c = pp[1];
            #pragma unroll
            for (int j = 0; j < 4; ++j) { v[j] = f2b(a[j]); v[4 + j] = f2b(c[j]); }
        } else {
            v = *(const bf16x8*)((const short*)src + base);
        }
        int row = base >> 8, k = base & 255;            // W is [256 out][256 k]
        int s = k >> 5, quad = (k >> 3) & 3;
        int pc = (row << 2) + (quad ^ ((row >> 1) & 3));
        *(bf16x8*)(wb + mat * (FF * FF) + s * 8192 + pc * 8) = v;
    } else {
        #pragma unroll
        for (int mat = 0; mat < 3; ++mat) {
            const void* src = mat == 0 ? bq : mat == 1 ? bk : bv;
            int isf = flags[3 + mat * 2];
            int i = threadIdx.x;
            bb[mat * FF + i] = isf ? ((const float*)src)[i]
                                   : b2f(((const short*)src)[i]);
        }
    }
}

// ---------------------------------------------------------------------------
// Projection GEMM, 32 rows/wave: block = 2 waves x 32 rows = 64 rows, 128
// threads.  Each B-fragment ds_read feeds TWO MFMAs (row-groups 0/1) ->
// LDS-pipe work per output row halves vs 16 rows/wave.  Grid is flat:
// logical work id w (after bijective XCD swizzle) -> xb = w/nmats (row
// panel), mat = matbase + w%nmats.  mat-fastest order + XCD swizzle puts
// the 2-3 blocks sharing an x panel on the SAME XCD L2 -> x fetched ~once.
// Per mat: 8-step K-loop, double-buffered 16 KB W slabs via global_load_lds,
// 16 ds_read_b128 + 32 MFMA per wave per step, one __syncthreads per step.
// LDS = 32 KB; epilogue reuses it (16 KB wave-private) for coalesced stores.
// ---------------------------------------------------------------------------
__global__ __launch_bounds__(128, 2) void qkv_gemm(
    const void* __restrict__ x, const short* __restrict__ wb,
    const float* __restrict__ bb, short* __restrict__ qo,
    short* __restrict__ ko, float* __restrict__ vo,
    const int* __restrict__ flags, int matbase, int nmats)
{
    __shared__ __align__(16) short wlds[2][8192];       // 2 x 16 KB W slabs
    const int isf32x = flags[0];
    const int tid = threadIdx.x, wave = tid >> 6, lane = tid & 63;
    const int l16 = lane & 15, quad = lane >> 4;

    const int nwg = 782 * nmats;
    const int w = xcd_swz(blockIdx.x, nwg);
    const int xb = w / nmats;
    const int mat = matbase + (w - xb * nmats);

    const short* W = wb + mat * (FF * FF);              // slab-major
    const int rows0 = xb * 64 + wave * 32;

    // per-lane ds_read offset within a slab (shorts); +c*512 per fragment
    const int rdo = l16 * 32 + ((quad ^ ((l16 >> 1) & 3)) << 3);
    const int koff = quad * 8;

    // ---- preload x fragments for both row-groups, all 8 K-steps ----
    bf16x8 afrag[2][8];
    #pragma unroll
    for (int rg = 0; rg < 2; ++rg) {
        const int rowa = rows0 + rg * 16 + l16;
        const int rowc = rowa < NN ? rowa : NN - 1;
        const size_t xrow = (size_t)rowc * FF;
        if (isf32x) {
            #pragma unroll
            for (int s = 0; s < 8; ++s) {
                const f32x4* p = (const f32x4*)((const float*)x + xrow + s * 32 + koff);
                f32x4 u = p[0], v2 = p[1];
                #pragma unroll
                for (int j = 0; j < 4; ++j) {
                    afrag[rg][s][j]     = f2b(u[j]);
                    afrag[rg][s][4 + j] = f2b(v2[j]);
                }
            }
        } else {
            #pragma unroll
            for (int s = 0; s < 8; ++s)
                afrag[rg][s] = *(const bf16x8*)((const short*)x + xrow + s * 32 + koff);
        }
    }

    // stage slab s of W into buffer buf: 1024 chunks of 16 B, 8/thread;
    // wave-uniform LDS base = chunk (i*128 + wave*64), lane adds +lane.
    #define STAGE(buf, s) do {                                                  \
        const short* gs_ = W + (s) * 8192;                                      \
        _Pragma("unroll")                                                       \
        for (int i_ = 0; i_ < 8; ++i_)                                          \
            gld16(&wlds[buf][(i_ * 128 + (tid & ~63)) * 8],                     \
                  gs_ + (size_t)(i_ * 128 + tid) * 8);                          \
    } while (0)

    STAGE(0, 0);
    __syncthreads();                                    // slab 0 resident

    f32x4 acc[2][16] = {};
    #pragma unroll
    for (int s = 0; s < 8; ++s) {
        const int cur = s & 1;
        if (s < 7) STAGE(cur ^ 1, s + 1);
        const short* ws0 = &wlds[cur][rdo];
        #pragma unroll
        for (int c = 0; c < 16; ++c) {
            bf16x8 bf = *(const bf16x8*)(ws0 + c * 512);
            acc[0][c] = __builtin_amdgcn_mfma_f32_16x16x32_bf16(afrag[0][s], bf, acc[0][c], 0, 0, 0);
            acc[1][c] = __builtin_amdgcn_mfma_f32_16x16x32_bf16(afrag[1][s], bf, acc[1][c], 0, 0, 0);
        }
        __syncthreads();   // all waves done with cur; next slab drained
    }
    #undef STAGE

    // ---- epilogue: reuse wlds; 16 KB wave-private slice ----
    // C/D layout: col = c*16 + (lane&15), row = quad*4 + reg  [m89-verified]
    const float* bias = bb + mat * FF;
    short* slice = (short*)wlds + wave * 8192;          // 16 KB per wave

    if (mat == 2) {
        // V: fp32, permuted cols pc = (col&31)*8 + col>>5.  Two rounds split
        // by c&1 -> contiguous 512 B per row per round (32 rows x 128 f32).
        float* lsf = (float*)slice;
        #pragma unroll
        for (int h = 0; h < 2; ++h) {
            #pragma unroll
            for (int rg = 0; rg < 2; ++rg)
                #pragma unroll
                for (int ci = 0; ci < 8; ++ci) {
                    int c = ci * 2 + h;                 // c & 1 == h
                    int col = c * 16 + l16;
                    float bv = bias[col];
                    int pcl = l16 * 8 + ci;             // pc - h*128, in [0,128)
                    #pragma unroll
                    for (int rr = 0; rr < 4; ++rr)
                        lsf[(rg * 16 + quad * 4 + rr) * 128 + pcl] = acc[rg][c][rr] + bv;
                }
            #pragma unroll
            for (int it = 0; it < 16; ++it) {           // 1024 chunks of 16 B
                int idx = it * 64 + lane;
                int r = idx >> 5, cc = idx & 31;
                int row = rows0 + r;
                if (row < NN)
                    *(f32x4*)(vo + (size_t)row * FF + h * 128 + cc * 4) =
                        ((const f32x4*)lsf)[idx];
            }
        }
    } else {
        // Q/K: bf16, 32 rows x 256 shorts = 16 KB exact.
        #pragma unroll
        for (int rg = 0; rg < 2; ++rg)
            #pragma unroll
            for (int c = 0; c < 16; ++c) {
                int col = c * 16 + l16;
                float bv = bias[col];
                #pragma unroll
                for (int rr = 0; rr < 4; ++rr)
                    slice[(rg * 16 + quad * 4 + rr) * 256 + col] = f2b(acc[rg][c][rr] + bv);
            }
        short* out = (mat == 0) ? qo : ko;
        #pragma unroll
        for (int it = 0; it < 16; ++it) {               // 1024 chunks of 16 B
            int idx = it * 64 + lane;
            int r = idx >> 5, cc = idx & 31;
            int row = rows0 + r;
            if (row < NN)
                *(bf16x8*)(out + (size_t)row * FF + cc * 8) =
                    *(const bf16x8*)(slice + r * 256 + cc * 8);
        }
    }
}

// ---------------------------------------------------------------------------
// Edge phase. Pass A: exp -> (optional ws stage) + atomicAdd into sums.
// rsum: sums -> 1/(sums+eps) in place. Pass B: att = exp * rsum (exp from
// ws if staged, else recomputed bit-identically). Segment-max skipped:
// logits ~ N(0,~0.1), overflow-free.
// ---------------------------------------------------------------------------
__device__ __forceinline__ float edge_exp_f(
    const int* __restrict__ edge, const void* __restrict__ ew,
    const short* __restrict__ q, const short* __restrict__ k,
    int t, int isf32, int is64, int* s_out)
{
    int e = t >> 3, h = t & 7;
    int s = is64 ? edge[2 * (size_t)e] : edge[e];
    int d = is64 ? edge[2 * ((size_t)EE + e)] : edge[EE + e];
    *s_out = s;
    const short* qp = q + (size_t)s * FF + h * DK;
    const short* kp = k + (size_t)d * FF + h * DK;
    float dot = 0.f;
    #pragma unroll
    for (int i = 0; i < 4; ++i) {
        bf16x8 qa = *(const bf16x8*)(qp + i * 8);
        bf16x8 ka = *(const bf16x8*)(kp + i * 8);
        #pragma unroll
        for (int j = 0; j < 8; ++j) dot += b2f(qa[j]) * b2f(ka[j]);
    }
    float w = isf32 ? ((const float*)ew)[e] : b2f(((const short*)ew)[e]);
    return __expf(dot * 0.17677669529663687f * w);   // 1/sqrt(32)
}

__global__ __launch_bounds__(256) void edge_pass_a(
    const int* __restrict__ edge, const void* __restrict__ ew,
    const short* __restrict__ q, const short* __restrict__ k,
    float* __restrict__ sums, float* __restrict__ expbuf,
    const int* __restrict__ flags, int use_exp)
{
    int t = blockIdx.x * 256 + threadIdx.x;   // t < E*H exactly
    int s;
    float exv = edge_exp_f(edge, ew, q, k, t, flags[1], flags[8], &s);
    if (use_exp) expbuf[t] = exv;
    atomicAdd(&sums[s * HH + (threadIdx.x & 7)], exv);
}

__global__ __launch_bounds__(256) void rsum_inv(float* __restrict__ sums)
{
    int i = blockIdx.x * 256 + threadIdx.x;
    if (i < NN * HH) sums[i] = 1.0f / (sums[i] + 1e-16f);
}

__global__ __launch_bounds__(256) void edge_pass_b(
    const int* __restrict__ edge, const void* __restrict__ ew,
    const short* __restrict__ q, const short* __restrict__ k,
    const float* __restrict__ sums, const float* __restrict__ expbuf,
    float* __restrict__ att, const int* __restrict__ flags, int use_exp)
{
    int t = blockIdx.x * 256 + threadIdx.x;
    float exv; int s;
    if (use_exp) {
        int e = t >> 3;
        s = flags[8] ? edge[2 * (size_t)e] : edge[e];
        exv = expbuf[t];
    } else {
        exv = edge_exp_f(edge, ew, q, k, t, flags[1], flags[8], &s);
    }
    att[t] = exv * sums[s * HH + (t & 7)];
}

extern "C" void kernel_launch(void* const* d_in, const int* in_sizes, int n_in,
                              void* d_out, int out_size, void* d_ws, size_t ws_size,
                              hipStream_t stream) {
    const void* x    = d_in[0];
    const int*  edge = (const int*)d_in[1];
    const void* ew   = d_in[2];
    const void* Wq   = d_in[3];
    const void* bq   = d_in[4];
    const void* Wk   = d_in[5];
    const void* bk   = d_in[6];
    const void* Wv   = d_in[7];
    const void* bv   = d_in[8];

    float* att_out = (float*)d_out;                 // fp32 [E,H]
    float* v_out   = att_out + (size_t)EE * HH;     // fp32 [N,DK,H]

    // ws: flags(256B) | sums N*H f32 | q_ bf16 | wb bf16 x3 | bb f32 x3 |
    //     expb f32 [E,H]? | k_ bf16?
    char*  ws    = (char*)d_ws;
    int*   flags = (int*)ws;
    float* sums  = (float*)(ws + 256);
    const size_t SUMS_B = (size_t)NN * HH * 4;      // 1.6 MB
    const size_t Q_B    = (size_t)NN * FF * 2;      // 25.6 MB
    const size_t EXP_B  = (size_t)EE * HH * 4;      // 25.6 MB
    short* q_  = (short*)(ws + 256 + SUMS_B);
    short* wb  = (short*)(ws + 256 + SUMS_B + Q_B);
    float* bb  = (float*)(ws + 256 + SUMS_B + Q_B + 3 * FF * FF * 2);
    float* expb = (float*)(ws + 256 + SUMS_B + Q_B + 3 * FF * FF * 2 + 3 * FF * 4);
    const size_t BASE_B = 256 + SUMS_B + Q_B + 3 * FF * FF * 2 + 3 * FF * 4;
    const int use_exp = (ws_size >= BASE_B + EXP_B) ? 1 : 0;
    const int fused   = (ws_size >= BASE_B + EXP_B + Q_B) ? 1 : 0;

    sniff_all<<<9, 256, 0, stream>>>(x, ew, Wq, bq, Wk, bk, Wv, bv, edge, flags);
    convert_wb<<<97, 256, 0, stream>>>(Wq, Wk, Wv, bq, bk, bv, wb, bb, flags);
    hipMemsetAsync(sums, 0, SUMS_B, stream);

    const int nEH = EE * HH;                        // 6.4M, % 256 == 0

    if (fused) {
        // k_ lives in ws -> one flat QKV GEMM dispatch (mat = w%3, XCD-local
        // x panels), then edge phase.
        short* k_ = (short*)(ws + BASE_B + EXP_B);
        qkv_gemm<<<782 * 3, 128, 0, stream>>>(x, wb, bb, q_, k_, v_out, flags, 0, 3);
        edge_pass_a<<<nEH / 256, 256, 0, stream>>>(edge, ew, q_, k_, sums, expb, flags, 1);
        rsum_inv<<<(NN * HH + 255) / 256, 256, 0, stream>>>(sums);
        edge_pass_b<<<nEH / 256, 256, 0, stream>>>(edge, ew, q_, k_, sums, expb, att_out, flags, 1);
    } else {
        // K staged bf16 inside the fp32 v-output region; V GEMM runs last.
        short* k_ = (short*)v_out;
        qkv_gemm<<<782 * 2, 128, 0, stream>>>(x, wb, bb, q_, k_, nullptr, flags, 0, 2);
        edge_pass_a<<<nEH / 256, 256, 0, stream>>>(edge, ew, q_, k_, sums, expb, flags, use_exp);
        rsum_inv<<<(NN * HH + 255) / 256, 256, 0, stream>>>(sums);
        edge_pass_b<<<nEH / 256, 256, 0, stream>>>(edge, ew, q_, k_, sums, expb, att_out, flags, use_exp);
        qkv_gemm<<<782, 128, 0, stream>>>(x, wb, bb, nullptr, nullptr, v_out, flags, 2, 1);
    }
}